// Round 10
// baseline (328.917 us; speedup 1.0000x reference)
//
#include <hip/hip_runtime.h>
#include <math.h>

#define N_NODES  100000
#define N_EDGES  1600000
#define HIDDEN   128
#define CAP      32        // bucket slots per node (deg ~ Poisson(16))
#define OVF_CAP  8192      // overflow edge capacity

// clang ext_vector types for nontemporal builtins (HIP_vector_type is rejected)
typedef int            vi4  __attribute__((ext_vector_type(4)));
typedef float          vf4  __attribute__((ext_vector_type(4)));
typedef unsigned short vus4 __attribute__((ext_vector_type(4)));

// float -> bf16 with round-to-nearest-even
__device__ inline unsigned short f2bf(float f) {
    unsigned u = __float_as_uint(f);
    u += 0x7FFF + ((u >> 16) & 1);
    return (unsigned short)(u >> 16);
}

// ---------------- Kernel 1: scores + x->bf16 conversion + init -------------
// One wave per 2 nodes: half-wave h handles node 2*wave+h; lane reads float4.
// Also emits xb (bf16 copy of x) and zeroes cnt/sum/ovf_cnt (no memset launch).
__global__ void scores_kernel(const float* __restrict__ x,
                              const float* __restrict__ W,
                              const float* __restrict__ b,
                              float* __restrict__ scores,
                              int* __restrict__ cnt,
                              unsigned short* __restrict__ xb,
                              double* __restrict__ sum,
                              int* __restrict__ ovf_cnt) {
    if (blockIdx.x == 0 && threadIdx.x == 0) {
        *sum = 0.0;
        *ovf_cnt = 0;
    }
    int wave = (blockIdx.x * blockDim.x + threadIdx.x) >> 6;
    int lane = threadIdx.x & 63;
    int h = lane >> 5, l32 = lane & 31;
    int n = wave * 2 + h;
    if (n >= N_NODES) return;
    float4 xv = *reinterpret_cast<const float4*>(x + (size_t)n * HIDDEN + l32 * 4);
    float4 wv = *reinterpret_cast<const float4*>(W + l32 * 4);
    vus4 bv;
    bv.x = f2bf(xv.x); bv.y = f2bf(xv.y); bv.z = f2bf(xv.z); bv.w = f2bf(xv.w);
    *reinterpret_cast<vus4*>(xb + (size_t)n * HIDDEN + l32 * 4) = bv;
    float d = xv.x * wv.x + xv.y * wv.y + xv.z * wv.z + xv.w * wv.w;
#pragma unroll
    for (int off = 16; off > 0; off >>= 1)       // halves reduce independently
        d += __shfl_xor(d, off, 64);
    if (l32 == 0) {
        scores[n] = 1.0f / (1.0f + expf(-(d + b[0])));
        cnt[n] = 0;
    }
}

// -------- Kernel 2 (fused): energy -> exp, global sum, direct bucket fill ----
// 4 edges per thread (1563 blocks -> 2x the waves of the 8/thread version;
// the kernel is latency-bound on the cnt atomics). All 4 atomics issue before
// any dependent store so each thread keeps 4 in flight by construction.
// energy in [0,1) so exp never overflows (max-subtraction redundant).
__global__ void energy_bucket_kernel(const int* __restrict__ ei,
                                     const float* __restrict__ ew,
                                     const float* __restrict__ scores,
                                     double* __restrict__ sum,
                                     int* __restrict__ cnt,
                                     float2* __restrict__ ebuf,
                                     int* __restrict__ ovf_cnt,
                                     float4* __restrict__ ovf) {
    int t = blockIdx.x * blockDim.x + threadIdx.x;
    double local = 0.0;
    if (t < N_EDGES / 4) {
        vi4 r4 = __builtin_nontemporal_load(reinterpret_cast<const vi4*>(ei) + t);
        vi4 c4 = __builtin_nontemporal_load(reinterpret_cast<const vi4*>(ei + N_EDGES) + t);
        vf4 w4 = __builtin_nontemporal_load(reinterpret_cast<const vf4*>(ew) + t);
        int   rs[4]  = {r4.x, r4.y, r4.z, r4.w};
        int   cs[4]  = {c4.x, c4.y, c4.z, c4.w};
        float wsv[4] = {w4.x, w4.y, w4.z, w4.w};
        float pe[4];
        int   pos[4];
#pragma unroll
        for (int k = 0; k < 4; ++k)
            pe[k] = expf(scores[rs[k]] * scores[cs[k]] * wsv[k]);
#pragma unroll
        for (int k = 0; k < 4; ++k)
            pos[k] = atomicAdd(&cnt[rs[k]], 1);
#pragma unroll
        for (int k = 0; k < 4; ++k) {
            local += (double)pe[k];
            if (pos[k] < CAP) {
                ebuf[(size_t)rs[k] * CAP + pos[k]] =
                    make_float2(__int_as_float(cs[k]), pe[k]);
            } else {
                int oi = atomicAdd(ovf_cnt, 1);
                if (oi < OVF_CAP)
                    ovf[oi] = make_float4(__int_as_float(rs[k]),
                                          __int_as_float(cs[k]), pe[k], 0.f);
            }
        }
    }
#pragma unroll
    for (int off = 32; off > 0; off >>= 1)
        local += __shfl_xor(local, off, 64);
    __shared__ double part[4];
    int lane = threadIdx.x & 63, w = threadIdx.x >> 6;
    if (lane == 0) part[w] = local;
    __syncthreads();
    if (threadIdx.x == 0)
        atomicAdd(sum, part[0] + part[1] + part[2] + part[3]);
}

// ---------------- Kernel 3: per-node accumulate (no atomics, bf16 gather) ---
// One wave per node; quarter-wave q handles edge j+q: 16 lanes x 16B (uint4)
// = full 256B bf16 row. Lane l16 owns features [l16*8, l16*8+8).
__global__ void accumulate_kernel(const unsigned short* __restrict__ xb,
                                  const int* __restrict__ cnt,
                                  const float2* __restrict__ ebuf,
                                  const double* __restrict__ sum,
                                  float* __restrict__ out) {
    int n    = (blockIdx.x * blockDim.x + threadIdx.x) >> 6;
    int lane = threadIdx.x & 63;
    if (n >= N_NODES) return;
    int deg = cnt[n];
    if (deg > CAP) deg = CAP;
    int q = lane >> 4, l16 = lane & 15;
    const float2* rec = ebuf + (size_t)n * CAP;
    float acc[8] = {0.f, 0.f, 0.f, 0.f, 0.f, 0.f, 0.f, 0.f};

    auto fma_row = [&](float2 r0) {
        int   c = __float_as_int(r0.x);
        float w = r0.y;
        uint4 a = *reinterpret_cast<const uint4*>(xb + (size_t)c * HIDDEN + l16 * 8);
        unsigned uu[4] = {a.x, a.y, a.z, a.w};
#pragma unroll
        for (int k = 0; k < 4; ++k) {
            acc[2 * k]     += __uint_as_float(uu[k] << 16) * w;
            acc[2 * k + 1] += __uint_as_float(uu[k] & 0xFFFF0000u) * w;
        }
    };

    int j = 0;
    for (; j + 16 <= deg; j += 16) {
        float2 r0 = rec[j + q];
        float2 r1 = rec[j + 4 + q];
        float2 r2 = rec[j + 8 + q];
        float2 r3 = rec[j + 12 + q];
        fma_row(r0); fma_row(r1); fma_row(r2); fma_row(r3);
    }
    for (; j + 8 <= deg; j += 8) {
        float2 r0 = rec[j + q];
        float2 r1 = rec[j + 4 + q];
        fma_row(r0); fma_row(r1);
    }
    for (; j < deg; j += 4) {
        if (j + q < deg) {
            float2 r0 = rec[j + q];
            fma_row(r0);
        }
    }
#pragma unroll
    for (int k = 0; k < 8; ++k) {
        acc[k] += __shfl_xor(acc[k], 16, 64);
        acc[k] += __shfl_xor(acc[k], 32, 64);
    }
    if (q == 0) {
        float inv = (float)(1.0 / sum[0]);
        float4 o0 = make_float4(acc[0] * inv, acc[1] * inv, acc[2] * inv, acc[3] * inv);
        float4 o1 = make_float4(acc[4] * inv, acc[5] * inv, acc[6] * inv, acc[7] * inv);
        float* op = out + (size_t)n * HIDDEN + l16 * 8;
        *reinterpret_cast<float4*>(op)     = o0;
        *reinterpret_cast<float4*>(op + 4) = o1;
    }
}

// ---------------- Kernel 4: overflow fixup (runs after accumulate) ----------
// Uses full-precision x (few edges; exactness there is free).
__global__ void overflow_kernel(const float* __restrict__ x,
                                const float4* __restrict__ ovf,
                                const int* __restrict__ ovf_cnt,
                                const double* __restrict__ sum,
                                float* __restrict__ out) {
    int cnt = *ovf_cnt;
    if (cnt > OVF_CAP) cnt = OVF_CAP;
    float inv = (float)(1.0 / sum[0]);
    int wid  = (blockIdx.x * blockDim.x + threadIdx.x) >> 6;
    int lane = threadIdx.x & 63;
    int nw   = (gridDim.x * blockDim.x) >> 6;
    for (int i = wid; i < cnt; i += nw) {
        float4 rc = ovf[i];
        int r = __float_as_int(rc.x);
        int c = __float_as_int(rc.y);
        float a = rc.z * inv;
        const float2 xv = *reinterpret_cast<const float2*>(x + (size_t)c * HIDDEN + lane * 2);
        float* o = out + (size_t)r * HIDDEN + lane * 2;
        atomicAdd(o,     xv.x * a);
        atomicAdd(o + 1, xv.y * a);
    }
}

extern "C" void kernel_launch(void* const* d_in, const int* in_sizes, int n_in,
                              void* d_out, int out_size, void* d_ws, size_t ws_size,
                              hipStream_t stream) {
    const float* x   = (const float*)d_in[0];
    const int*   ei  = (const int*)d_in[1];    // harness stages integers as int32
    const float* ew  = (const float*)d_in[2];
    const float* W   = (const float*)d_in[3];
    const float* b   = (const float*)d_in[4];
    float*       out = (float*)d_out;

    // Workspace layout (all 16-aligned):
    // [0,8)                double sum
    // [8,12)               int    ovf_cnt
    // [16,400016)          int    cnt[N_NODES]
    // [400016,800016)      float  scores[N_NODES]
    // [800016,931088)      float4 ovf[OVF_CAP]
    // [931088,26531088)    float2 ebuf[N_NODES*CAP]          (25.6MB)
    // [26531088,52131088)  ushort xb[N_NODES*HIDDEN] (bf16)  (25.6MB)
    char* ws = (char*)d_ws;
    double*         sum     = (double*)ws;
    int*            ovf_cnt = (int*)(ws + 8);
    int*            cnt     = (int*)(ws + 16);
    float*          scores  = (float*)(ws + 400016);
    float4*         ovf     = (float4*)(ws + 800016);
    float2*         ebuf    = (float2*)(ws + 931088);
    unsigned short* xb      = (unsigned short*)(ws + 26531088);

    // 2 nodes per wave, 4 waves per block -> 8 nodes/block; also zeroes
    // cnt/sum/ovf_cnt (no separate memset launch).
    scores_kernel<<<(N_NODES + 7) / 8, 256, 0, stream>>>(x, W, b, scores, cnt, xb,
                                                         sum, ovf_cnt);
    energy_bucket_kernel<<<(N_EDGES / 4 + 255) / 256, 256, 0, stream>>>(
        ei, ew, scores, sum, cnt, ebuf, ovf_cnt, ovf);
    accumulate_kernel<<<(N_NODES + 3) / 4, 256, 0, stream>>>(xb, cnt, ebuf, sum, out);
    overflow_kernel<<<16, 256, 0, stream>>>(x, ovf, ovf_cnt, sum, out);
}